// Round 2
// 1707.096 us; speedup vs baseline: 1.4298x; 1.4298x over previous
//
#include <hip/hip_runtime.h>

#define BATCH 4096

typedef __attribute__((ext_vector_type(8))) short bf16x8;
typedef __attribute__((ext_vector_type(4))) float f32x4;

// Manual RNE float->bf16 (round half to even), matches HW/NumPy for normal finite values.
__device__ __forceinline__ unsigned short f2bf(float f) {
    union { float f; unsigned u; } v; v.f = f;
    unsigned r = v.u + 0x7fffu + ((v.u >> 16) & 1u);
    return (unsigned short)(r >> 16);
}
__device__ __forceinline__ unsigned packbf(float a, float b) {
    return (unsigned)f2bf(a) | ((unsigned)f2bf(b) << 16);
}

// 16 features for one x: o[0..3] = cos(1x..8x) pairs, o[4..7] = sin(1x..8x) pairs (bf16x2).
__device__ __forceinline__ void feats16(float x, unsigned o[8]) {
    float c1 = __cosf(x), s1 = __sinf(x);
    float cs[8], sn[8];
    cs[0] = c1; sn[0] = s1;
    #pragma unroll
    for (int k = 1; k < 8; ++k) {
        cs[k] = c1 * cs[k-1] - s1 * sn[k-1];
        sn[k] = s1 * cs[k-1] + c1 * sn[k-1];
    }
    #pragma unroll
    for (int k = 0; k < 4; ++k) {
        o[k]     = packbf(cs[2*k], cs[2*k+1]);
        o[4 + k] = packbf(sn[2*k], sn[2*k+1]);
    }
}

// Async global->LDS, 16 B per lane. LDS dest is wave-uniform base; HW adds lane*16.
__device__ __forceinline__ void gload_lds16(const void* g, void* l) {
    __builtin_amdgcn_global_load_lds(
        (__attribute__((address_space(1))) void*)(g),
        (__attribute__((address_space(3))) void*)(l), 16, 0, 0);
}

// ---------------- one-shot precompute kernels ----------------

// C [2][OUT][IN][8] f32  ->  B [OUT][IN*16] bf16, k = i*16 + d*8 + g
// (matches feats16 output order: t=0..7 cos, 8..15 sin)
template <int IN, int OUT>
__global__ void conv_C(const float* __restrict__ C, unsigned short* __restrict__ B) {
    const int i = blockIdx.x * 256 + threadIdx.x;
    const int j = blockIdx.y;
    const float* c0 = C + ((size_t)j * IN + i) * 8;            // d=0 (cos) plane
    const float* c1 = c0 + (size_t)OUT * IN * 8;               // d=1 (sin) plane
    const float4 a0 = *(const float4*)c0;
    const float4 a1 = *(const float4*)(c0 + 4);
    const float4 s0 = *(const float4*)c1;
    const float4 s1 = *(const float4*)(c1 + 4);
    unsigned short* dst = B + ((size_t)j * IN + i) * 16;
    *(uint4*)dst       = make_uint4(packbf(a0.x, a0.y), packbf(a0.z, a0.w),
                                    packbf(a1.x, a1.y), packbf(a1.z, a1.w));
    *(uint4*)(dst + 8) = make_uint4(packbf(s0.x, s0.y), packbf(s0.z, s0.w),
                                    packbf(s1.x, s1.y), packbf(s1.z, s1.w));
}

// x [4096][768] f32 -> A1 [4096][768*16] bf16 (features of the input layer)
__global__ void feats_x_kernel(const float* __restrict__ x, unsigned short* __restrict__ A) {
    const size_t idx = (size_t)blockIdx.x * 256 + threadIdx.x;   // (b,i) linear
    unsigned o[8];
    feats16(x[idx], o);
    unsigned short* dst = A + idx * 16;
    *(uint4*)dst       = make_uint4(o[0], o[1], o[2], o[3]);
    *(uint4*)(dst + 8) = make_uint4(o[4], o[5], o[6], o[7]);
}

// Deterministic split-K reduction: out[b][j] = sum_z P[z][b][j] + bias[j].
// Fixed summation order -> bitwise-identical output every call.
template <int N, int KSPLIT>
__global__ void reduce_out(const float* __restrict__ P, const float* __restrict__ bias,
                           float* __restrict__ out) {
    const size_t idx = ((size_t)blockIdx.x * 256 + threadIdx.x) * 4;   // float4 granule
    const int j = (int)(idx % N);                                       // N % 4 == 0
    float4 s = *(const float4*)(P + idx);
    #pragma unroll
    for (int z = 1; z < KSPLIT; ++z) {
        const float4 v = *(const float4*)(P + (size_t)z * BATCH * N + idx);
        s.x += v.x; s.y += v.y; s.z += v.z; s.w += v.w;
    }
    const float4 bv = *(const float4*)(bias + j);
    s.x += bv.x; s.y += bv.y; s.z += bv.z; s.w += bv.w;
    *(float4*)(out + idx) = s;
}

// ---------------- main bf16 GEMM (m97 structure) ----------------
// A [4096][K] bf16 row-major, B [N][K] bf16 row-major (B^T GEMM).
// Tile 128x128, BK=64, 4 waves (2x2), global_load_lds width-16 staging, 2 barriers/k-step.
// EPI: 0 = f32 out [4096][N]; 1 = feats16(acc+bias) -> bf16 [4096][N*16] (next layer's A);
//      2 = split-K f32 partial (no bias) -> outv + blockIdx.z * BATCH * N.
template <int K, int N, int EPI, int KSPLIT>
__global__ __launch_bounds__(256, 2)
void kan_gemm(const unsigned short* __restrict__ A,
              const unsigned short* __restrict__ B,
              const float* __restrict__ bias,
              void* __restrict__ outv)
{
    __shared__ unsigned short As[128 * 64];   // 16 KB, linear (required by global_load_lds)
    __shared__ unsigned short Bs[128 * 64];   // 16 KB

    const int tid  = threadIdx.x;
    const int lane = tid & 63;
    const int wave = tid >> 6;          // 0..3
    const int wm   = wave >> 1;         // wave row -> 64 batch rows
    const int wn   = wave & 1;          // wave col -> 64 out cols
    const int fr   = lane & 15;
    const int fq   = lane >> 4;

    // XCD-chunked bijective swizzle over the (bx,by) tile plane (NWG % 8 == 0 for all shapes)
    constexpr int NBX = BATCH / 128;
    constexpr int NBY = N / 128;
    constexpr int NWG = NBX * NBY;
    const int wg  = blockIdx.y * NBX + blockIdx.x;
    const int swz = (wg & 7) * (NWG >> 3) + (wg >> 3);
    const int row0 = (swz % NBX) * 128;   // batch
    const int col0 = (swz / NBX) * 128;   // out features

    constexpr int KCH = K / KSPLIT;
    const int k0 = (KSPLIT == 1) ? 0 : (int)blockIdx.z * KCH;

    const int srow = lane >> 3;           // 0..7: row within the wave's 8-row staging stripe
    const int scol = (lane & 7) * 16;     // byte col within the 128 B row

    f32x4 acc[4][4] = {};

    for (int kt = k0 >> 6; kt < (k0 + KCH) >> 6; ++kt) {
        __syncthreads();   // previous tile's ds_reads done before overwrite
        #pragma unroll
        for (int r = 0; r < 4; ++r) {
            const int rr = r * 32 + wave * 8;          // wave-uniform stripe base
            gload_lds16((const char*)A + ((size_t)(row0 + rr + srow) * K + (size_t)kt * 64) * 2 + scol,
                        (char*)&As[rr * 64]);
            gload_lds16((const char*)B + ((size_t)(col0 + rr + srow) * K + (size_t)kt * 64) * 2 + scol,
                        (char*)&Bs[rr * 64]);
        }
        __syncthreads();   // compiler emits vmcnt(0) drain here

        #pragma unroll
        for (int ks = 0; ks < 2; ++ks) {
            bf16x8 af[4], bfm[4];
            #pragma unroll
            for (int m = 0; m < 4; ++m)
                af[m] = *(const bf16x8*)&As[(wm * 64 + m * 16 + fr) * 64 + ks * 32 + fq * 8];
            #pragma unroll
            for (int n = 0; n < 4; ++n)
                bfm[n] = *(const bf16x8*)&Bs[(wn * 64 + n * 16 + fr) * 64 + ks * 32 + fq * 8];
            #pragma unroll
            for (int m = 0; m < 4; ++m)
                #pragma unroll
                for (int n = 0; n < 4; ++n)
                    acc[m][n] = __builtin_amdgcn_mfma_f32_16x16x32_bf16(
                        af[m], bfm[n], acc[m][n], 0, 0, 0);
        }
    }

    // Epilogue. C/D layout: col = lane&15 (N), row = (lane>>4)*4 + reg (M).
    #pragma unroll
    for (int n = 0; n < 4; ++n) {
        const int gc = col0 + wn * 64 + n * 16 + fr;
        const float bv = (EPI == 2) ? 0.0f : bias[gc];
        #pragma unroll
        for (int m = 0; m < 4; ++m) {
            const int gr0 = row0 + wm * 64 + m * 16 + fq * 4;
            #pragma unroll
            for (int q = 0; q < 4; ++q) {
                const float y = acc[m][n][q] + bv;
                if (EPI == 0) {
                    ((float*)outv)[(size_t)(gr0 + q) * N + gc] = y;
                } else if (EPI == 1) {
                    unsigned o[8];
                    feats16(y, o);   // features computed exactly once per (b,j)
                    unsigned short* dst = (unsigned short*)outv + ((size_t)(gr0 + q) * N + gc) * 16;
                    *(uint4*)dst       = make_uint4(o[0], o[1], o[2], o[3]);
                    *(uint4*)(dst + 8) = make_uint4(o[4], o[5], o[6], o[7]);
                } else {
                    // split-K partial: deterministic (no atomics); reduced by reduce_out.
                    ((float*)outv)[(size_t)blockIdx.z * BATCH * N +
                                   (size_t)(gr0 + q) * N + gc] = y;
                }
            }
        }
    }
}

extern "C" void kernel_launch(void* const* d_in, const int* in_sizes, int n_in,
                              void* d_out, int out_size, void* d_ws, size_t ws_size,
                              hipStream_t stream) {
    (void)in_sizes; (void)n_in; (void)ws_size; (void)out_size;
    const float* x  = (const float*)d_in[0];   // [4096][768]
    const float* C1 = (const float*)d_in[1];   // [2][2048][768][8]
    const float* b1 = (const float*)d_in[2];   // [2048]
    const float* C2 = (const float*)d_in[3];   // [2][2048][2048][8]
    const float* b2 = (const float*)d_in[4];   // [2048]
    const float* C3 = (const float*)d_in[5];   // [2][512][2048][8]
    const float* b3 = (const float*)d_in[6];   // [512]
    float* out = (float*)d_out;                // [4096][512]

    // Workspace layout (bf16), lifetime-aliased. Peak = 688 MiB.
    //   [0, A1) [A1, A1+B1) : layer-1 operands; B2 later aliases this whole region;
    //                         split-K partials P later alias [0, 33.5 MB) (B2 dead by then).
    //   A2 at 151 MB (written by gemm1 epi, read by gemm2); B3 later aliases A2.
    //   A3 at 419 MB (written by gemm2 epi, read by gemm3).
    char* ws = (char*)d_ws;
    const size_t SZ_A1 = (size_t)4096 * 12288 * 2;   // 100.66 MB
    const size_t SZ_B1 = (size_t)2048 * 12288 * 2;   //  50.33 MB
    const size_t SZ_A2 = (size_t)4096 * 32768 * 2;   // 268.44 MB
    unsigned short* A1 = (unsigned short*)(ws);
    unsigned short* B1 = (unsigned short*)(ws + SZ_A1);
    unsigned short* B2 = (unsigned short*)(ws);                    // 134.2 MB, aliases A1+B1
    unsigned short* A2 = (unsigned short*)(ws + SZ_A1 + SZ_B1);
    unsigned short* B3 = (unsigned short*)(ws + SZ_A1 + SZ_B1);    // 33.6 MB, aliases A2
    unsigned short* A3 = (unsigned short*)(ws + SZ_A1 + SZ_B1 + SZ_A2);
    float*          P  = (float*)(ws);                             // 33.5 MB, aliases dead B2

    // ---- layer 1: (4096 x 12288) x (2048 x 12288)^T -> feats -> A2
    conv_C<768, 2048><<<dim3(768 / 256, 2048), 256, 0, stream>>>(C1, B1);
    feats_x_kernel<<<dim3((4096 * 768) / 256), 256, 0, stream>>>(x, A1);
    kan_gemm<12288, 2048, 1, 1><<<dim3(32, 16), 256, 0, stream>>>(A1, B1, b1, A2);

    // ---- layer 2: (4096 x 32768) x (2048 x 32768)^T -> feats -> A3
    conv_C<2048, 2048><<<dim3(2048 / 256, 2048), 256, 0, stream>>>(C2, B2);   // after gemm1 (alias)
    kan_gemm<32768, 2048, 1, 1><<<dim3(32, 16), 256, 0, stream>>>(A2, B2, b2, A3);

    // ---- layer 3: (4096 x 32768) x (512 x 32768)^T, split-K x4, deterministic reduce
    conv_C<2048, 512><<<dim3(2048 / 256, 512), 256, 0, stream>>>(C3, B3);     // after gemm2 (alias)
    kan_gemm<32768, 512, 2, 4><<<dim3(32, 4, 4), 256, 0, stream>>>(A3, B3, b3, P);
    reduce_out<512, 4><<<dim3((BATCH * 512 / 4) / 256), 256, 0, stream>>>(P, b3, out);
}